// Round 12
// baseline (1862.326 us; speedup 1.0000x reference)
//
#include <hip/hip_runtime.h>
#include <math.h>

#define PIXN 4096

typedef _Float16 f16;

__device__ __forceinline__ f16 f2h(float f) { return (f16)f; }
__device__ __forceinline__ float h2f(f16 h) { return (float)h; }

enum { ACT_NONE = 0, ACT_LRELU = 1, ACT_SIG144 = 2 };
enum { IN_NCHW = 0, IN_FLAT = 1, IN_UVPAIR = 2 };
enum { OUT_FLAT = 0, OUT_NCHWRES = 1 };

// ---------------- fused weight prep (8 jobs) ----------------
__device__ __forceinline__ void wtrans_dev(const float* __restrict__ w, float* __restrict__ wT,
                                           int srcCIN, int cinOff, int dstCIN, int COUTv,
                                           int total, int idx) {
  if (idx >= total) return;
  int co = idx % COUTv;
  int t = idx / COUTv;
  int ci = t % dstCIN;
  int tap = t / dstCIN;
  wT[idx] = w[((long)co * srcCIN + cinOff + ci) * 9 + tap];
}

__global__ __launch_bounds__(256) void prep_all(
    const float* __restrict__ cf_w, const float* __restrict__ oc1_w,
    const float* __restrict__ oc2_w, const float* __restrict__ om_w,
    const float* __restrict__ cl_w, const float* __restrict__ om_b,
    const float* __restrict__ wq, const float* __restrict__ wk, const float* __restrict__ wv,
    const float* __restrict__ bq, const float* __restrict__ bk, const float* __restrict__ bv,
    float* __restrict__ T0, float* __restrict__ TAB, float* __restrict__ T2,
    float* __restrict__ T3, float* __restrict__ T4,
    float* __restrict__ WQKV, float* __restrict__ BQKV, float* __restrict__ B3p) {
  int idx = blockIdx.x * 256 + threadIdx.x;
  switch (blockIdx.y) {
    case 0: wtrans_dev(cf_w, T0, 64, 0, 64, 96, 55296, idx); break;
    case 1: wtrans_dev(oc1_w, TAB, 192, 0, 96, 96, 82944, idx); break;
    case 2: wtrans_dev(oc1_w, TAB + 82944, 192, 96, 96, 96, 82944, idx); break;
    case 3: wtrans_dev(oc2_w, T2, 96, 0, 96, 96, 82944, idx); break;
    case 4: {  // om weights padded to COUT=224 (oc>=216 -> 0)
      if (idx < 9 * 96 * 224) {
        int co = idx % 224;
        int t = idx / 224;
        int ci = t % 96;
        int tap = t / 96;
        T3[idx] = (co < 216) ? om_w[((long)co * 96 + ci) * 9 + tap] : 0.f;
      }
      break;
    }
    case 5: wtrans_dev(cl_w, T4, 96, 0, 96, 64, 55296, idx); break;
    case 6: {
      if (idx < 96 * 288) {
        int e288 = idx % 288;
        int c = idx / 288;
        int m = e288 / 96, e = e288 % 96;
        const float* wm = (m == 0) ? wq : (m == 1) ? wk : wv;
        WQKV[idx] = wm[e * 96 + c];
      }
      if (idx < 288) {
        int m = idx / 96, e = idx % 96;
        const float* bm = (m == 0) ? bq : (m == 1) ? bk : bv;
        BQKV[idx] = bm[e];
      }
      break;
    }
    default: {
      if (idx < 224) B3p[idx] = (idx < 216) ? om_b[idx] : 0.f;
    }
  }
}

// ---------------- fp32 3x3 conv, GEMV-style (v4) ----------------
// Block 256 = 4 waves = 4 output rows; all waves share one oc-slice.
// Weights thread-uniform -> s_load; LDS 6x66x8cin stride-9 = 14.3 KB.
// IN_UVPAIR: stage lrelu(U[jj] + V[ii] + bias_in) (fused off1).
template <int CIN, int COUT, int CG, int ACT, int IMODE, int OMODE, bool QKVIN>
__global__ __launch_bounds__(256) void conv3x3v4(
    const float* __restrict__ in, const float* __restrict__ in2,
    const float* __restrict__ bias_in,
    const float* __restrict__ wT,
    const float* __restrict__ bias,
    float* __restrict__ out,
    const float* __restrict__ resid) {
  constexpr int NOCG = COUT / CG;
  constexpr int NCH = CIN / 8;
  const int y0 = blockIdx.x * 4;
  const int iz = blockIdx.y;
  const int cg = blockIdx.z;
  const int tid = threadIdx.x;
  const int x = tid & 63;
  const int wv = tid >> 6;
  const int ocb = cg * NOCG;

  __shared__ float lds[6 * 66 * 9];

  const float* baseA;
  const float* baseB2 = nullptr;
  const float* wTe = wT;
  if constexpr (QKVIN) {
    int sel = iz / 12, img = iz % 12;
    baseA = in + (long)img * (PIXN * 288) + sel * 96;
    wTe = wT + (long)sel * (9 * 96 * COUT);
  } else if constexpr (IMODE == IN_UVPAIR) {
    int pair = iz >> 2, b = iz & 3;
    int jj = pair >> 1, rr = pair & 1;
    int ii = (rr == 0) ? (jj == 0 ? 1 : 0) : (jj == 2 ? 1 : 2);
    baseA = in + (long)(b * 3 + jj) * (PIXN * 96);
    baseB2 = in2 + (long)(b * 3 + ii) * (PIXN * 96);
  } else if constexpr (IMODE == IN_NCHW) {
    baseA = in + (long)iz * (CIN * PIXN);
  } else {
    baseA = in + (long)iz * (PIXN * CIN);
  }
  constexpr int LDV = QKVIN ? 288 : CIN;

  float acc[NOCG];
#pragma unroll
  for (int j = 0; j < NOCG; ++j) acc[j] = bias ? bias[ocb + j] : 0.f;

#pragma unroll 1
  for (int ch = 0; ch < NCH; ++ch) {
    __syncthreads();
    if constexpr (IMODE == IN_NCHW) {
      for (int i = tid; i < 8 * 396; i += 256) {
        int cin = i / 396;
        int t = i - cin * 396;
        int r = t / 66, px = t - r * 66;
        int yy = y0 - 1 + r, xx = px - 1;
        float v = 0.f;
        if ((unsigned)yy < 64u && (unsigned)xx < 64u)
          v = baseA[(long)(ch * 8 + cin) * PIXN + yy * 64 + xx];
        lds[t * 9 + cin] = v;
      }
    } else if constexpr (IMODE == IN_UVPAIR) {
      for (int i = tid; i < 396 * 2; i += 256) {
        int c4 = i & 1, t = i >> 1;
        int r = t / 66, px = t - r * 66;
        int yy = y0 - 1 + r, xx = px - 1;
        float4 rv = make_float4(0.f, 0.f, 0.f, 0.f);
        if ((unsigned)yy < 64u && (unsigned)xx < 64u) {
          long off = (long)(yy * 64 + xx) * 96 + ch * 8 + c4 * 4;
          float4 u = *reinterpret_cast<const float4*>(baseA + off);
          float4 vv = *reinterpret_cast<const float4*>(baseB2 + off);
          float4 bi = *reinterpret_cast<const float4*>(bias_in + ch * 8 + c4 * 4);
          rv.x = u.x + vv.x + bi.x; rv.x = rv.x >= 0.f ? rv.x : 0.1f * rv.x;
          rv.y = u.y + vv.y + bi.y; rv.y = rv.y >= 0.f ? rv.y : 0.1f * rv.y;
          rv.z = u.z + vv.z + bi.z; rv.z = rv.z >= 0.f ? rv.z : 0.1f * rv.z;
          rv.w = u.w + vv.w + bi.w; rv.w = rv.w >= 0.f ? rv.w : 0.1f * rv.w;
        }
        int b0 = t * 9 + c4 * 4;
        lds[b0] = rv.x; lds[b0 + 1] = rv.y; lds[b0 + 2] = rv.z; lds[b0 + 3] = rv.w;
      }
    } else {
      for (int i = tid; i < 396 * 2; i += 256) {
        int c4 = i & 1, t = i >> 1;
        int r = t / 66, px = t - r * 66;
        int yy = y0 - 1 + r, xx = px - 1;
        float4 v = make_float4(0.f, 0.f, 0.f, 0.f);
        if ((unsigned)yy < 64u && (unsigned)xx < 64u)
          v = *reinterpret_cast<const float4*>(
              baseA + (long)(yy * 64 + xx) * LDV + ch * 8 + c4 * 4);
        int b0 = t * 9 + c4 * 4;
        lds[b0] = v.x; lds[b0 + 1] = v.y; lds[b0 + 2] = v.z; lds[b0 + 3] = v.w;
      }
    }
    __syncthreads();

#pragma unroll
    for (int r = 0; r < 3; ++r) {
#pragma unroll
      for (int kx = 0; kx < 3; ++kx) {
        const float* wp = wTe + ((long)((r * 3 + kx) * CIN + ch * 8)) * COUT + ocb;
        const int lb = ((wv + r) * 66 + x + kx) * 9;
#pragma unroll 2
        for (int cin = 0; cin < 8; ++cin) {
          float xv = lds[lb + cin];
          const float* wpc = wp + cin * COUT;
#pragma unroll
          for (int j = 0; j < NOCG; ++j)
            acc[j] = fmaf(xv, wpc[j], acc[j]);
        }
      }
    }
  }

  const int yo = y0 + wv;
#pragma unroll
  for (int j = 0; j < NOCG; ++j) {
    if (ACT == ACT_LRELU) acc[j] = acc[j] >= 0.f ? acc[j] : 0.1f * acc[j];
    if (ACT == ACT_SIG144) {
      if (ocb + j >= 144) acc[j] = 1.f / (1.f + expf(-acc[j]));
    }
  }
  if constexpr (OMODE == OUT_FLAT) {
    float* orow = out + ((long)iz * PIXN + yo * 64 + x) * COUT + ocb;
#pragma unroll
    for (int j4 = 0; j4 < NOCG / 4; ++j4) {
      float4 v = make_float4(acc[j4 * 4], acc[j4 * 4 + 1], acc[j4 * 4 + 2], acc[j4 * 4 + 3]);
      *reinterpret_cast<float4*>(orow + j4 * 4) = v;
    }
  } else {
#pragma unroll
    for (int j = 0; j < NOCG; ++j) {
      int oc = ocb + j;
      long oo = (long)iz * (COUT * PIXN) + (long)oc * PIXN + yo * 64 + x;
      out[oo] = acc[j] + resid[oo];
    }
  }
}

// ---------------- 1x1 qkv projection, GEMV-style ----------------
__global__ __launch_bounds__(256) void gemm1x1v2(const float* __restrict__ in,
                                                 const float* __restrict__ wT,
                                                 const float* __restrict__ bias,
                                                 float* __restrict__ out) {
  const int pcb = blockIdx.x;
  const int img = blockIdx.y;
  const int cg = blockIdx.z;
  const int tid = threadIdx.x;
  __shared__ float lds[256 * 33];
  float acc[96];
#pragma unroll
  for (int j = 0; j < 96; ++j) acc[j] = bias[cg * 96 + j];
  const float* ibase = in + ((long)img * PIXN + pcb * 256) * 96;
#pragma unroll 1
  for (int cc = 0; cc < 96; cc += 32) {
    __syncthreads();
    for (int i = tid; i < 2048; i += 256) {
      int px = i >> 3, c4 = i & 7;
      float4 v = *reinterpret_cast<const float4*>(ibase + (long)px * 96 + cc + c4 * 4);
      int b0 = px * 33 + c4 * 4;
      lds[b0] = v.x; lds[b0 + 1] = v.y; lds[b0 + 2] = v.z; lds[b0 + 3] = v.w;
    }
    __syncthreads();
#pragma unroll 2
    for (int c = 0; c < 32; ++c) {
      float xv = lds[tid * 33 + c];
      const float* wp = wT + (long)(cc + c) * 288 + cg * 96;
#pragma unroll
      for (int j = 0; j < 96; ++j) acc[j] = fmaf(xv, wp[j], acc[j]);
    }
  }
  float* orow = out + ((long)img * PIXN + pcb * 256 + tid) * 288 + cg * 96;
#pragma unroll
  for (int j4 = 0; j4 < 24; ++j4) {
    float4 v = make_float4(acc[j4 * 4], acc[j4 * 4 + 1], acc[j4 * 4 + 2], acc[j4 * 4 + 3]);
    *reinterpret_cast<float4*>(orow + j4 * 4) = v;
  }
}

// ---------------- deformable sampling helpers (fp32; mask pre-sigmoided) ----------------
__device__ __forceinline__ float dsampK(const float* __restrict__ kimg,
                                        const float* __restrict__ s_om,
                                        int g, int n, int y, int x, int c) {
  float oy = s_om[g * 9 + n];
  float ox = s_om[72 + g * 9 + n];
  float m = s_om[144 + g * 9 + n];
  float py = oy + (float)(y + n / 3 - 1);
  float px = ox + (float)(x + n % 3 - 1);
  float y0 = floorf(py), x0 = floorf(px);
  float wy = py - y0, wx = px - x0;
  float acc = 0.f;
#pragma unroll
  for (int dy = 0; dy < 2; ++dy) {
#pragma unroll
    for (int dx = 0; dx < 2; ++dx) {
      float yc = y0 + dy, xc = x0 + dx;
      if (yc >= 0.f && yc < 64.f && xc >= 0.f && xc < 64.f) {
        float w = (dy ? wy : 1.f - wy) * (dx ? wx : 1.f - wx);
        acc = fmaf(w, kimg[(long)((int)yc * 64 + (int)xc) * 288 + 96 + c], acc);
      }
    }
  }
  return acc * m;
}

__device__ __forceinline__ float dsampV(const float* __restrict__ kimg,
                                        const float* __restrict__ s_om,
                                        int g, int n, int y, int x, int c) {
  float oy = s_om[g * 9 + n];
  float ox = s_om[72 + g * 9 + n];
  float m = s_om[144 + g * 9 + n];
  float py = oy + (float)(y + n / 3 - 1);
  float px = ox + (float)(x + n % 3 - 1);
  float y0 = floorf(py), x0 = floorf(px);
  float wy = py - y0, wx = px - x0;
  float acc = 0.f;
#pragma unroll
  for (int dy = 0; dy < 2; ++dy) {
#pragma unroll
    for (int dx = 0; dx < 2; ++dx) {
      float yc = y0 + dy, xc = x0 + dx;
      if (yc >= 0.f && yc < 64.f && xc >= 0.f && xc < 64.f) {
        float w = (dy ? wy : 1.f - wy) * (dx ? wx : 1.f - wx);
        acc = fmaf(w, kimg[(long)((int)yc * 64 + (int)xc) * 288 + 192 + c], acc);
      }
    }
  }
  return acc * m;
}

// ---------------- attn v2: 4 px/block, cached sampled-K, V-only select ----------------
// om stride = 224 (padded om layout; indices 0..215 semantic).
__global__ __launch_bounds__(256) void attn2_k(const float* __restrict__ qkv,
                                               const float* __restrict__ om,
                                               float* __restrict__ w_buf,
                                               f16* __restrict__ vre) {
  const int pair = blockIdx.y;
  const int jj = pair >> 1, rr = pair & 1;
  const int ii = (rr == 0) ? (jj == 0 ? 1 : 0) : (jj == 2 ? 1 : 2);
  const int wv = threadIdx.x >> 6;
  const int lane = threadIdx.x & 63;
  const int bp = blockIdx.x * 4 + wv;
  const int b = bp >> 12;
  const int p = bp & 4095;
  const int y = p >> 6, x = p & 63;

  __shared__ float s_om_all[4 * 216];
  float* s_om = s_om_all + wv * 216;
  const float* omrow = om + ((long)pair * 4 * PIXN + bp) * 224;
  for (int i = lane; i < 216; i += 64) s_om[i] = omrow[i];
  __syncthreads();

  const float* qrow = qkv + ((long)(b * 3 + jj) * PIXN + p) * 288;
  const float* kimg = qkv + (long)(b * 3 + ii) * PIXN * 288;
  float q0 = qrow[lane];
  float q1 = 0.f;
  if (lane < 32) q1 = qrow[64 + lane];
  const int c0 = lane, g0 = lane / 12;
  const int c1 = 64 + lane, g1 = (64 + lane) / 12;

  float rel[9], ka0[9], ka1[9];
#pragma unroll
  for (int n = 0; n < 9; ++n) {
    ka0[n] = dsampK(kimg, s_om, g0, n, y, x, c0);
    float part = q0 * ka0[n];
    ka1[n] = 0.f;
    if (lane < 32) {
      ka1[n] = dsampK(kimg, s_om, g1, n, y, x, c1);
      part = fmaf(q1, ka1[n], part);
    }
#pragma unroll
    for (int off = 32; off > 0; off >>= 1) part += __shfl_xor(part, off, 64);
    rel[n] = part;
  }
  int i0 = 0; float v0 = rel[0]; float ks00 = ka0[0], ks10 = ka1[0];
#pragma unroll
  for (int n = 1; n < 9; ++n) {
    bool t = rel[n] > v0;
    v0 = t ? rel[n] : v0; i0 = t ? n : i0;
    ks00 = t ? ka0[n] : ks00; ks10 = t ? ka1[n] : ks10;
  }
  int i1 = 0; float v1 = -3.4e38f; float ks01 = 0.f, ks11 = 0.f;
#pragma unroll
  for (int n = 0; n < 9; ++n) {
    bool t = (n != i0) && rel[n] > v1;
    v1 = t ? rel[n] : v1; i1 = t ? n : i1;
    ks01 = t ? ka0[n] : ks01; ks11 = t ? ka1[n] : ks11;
  }
  float e = expf(v1 - v0);
  float cw0 = 1.f / (1.f + e);
  float cw1 = e * cw0;

  float wpart = q0 * (cw0 * ks00 + cw1 * ks01);
  float va = dsampV(kimg, s_om, g0, i0, y, x, c0);
  float vb = dsampV(kimg, s_om, g0, i1, y, x, c0);
  vre[((long)pair * 16384 + bp) * 96 + c0] = f2h(cw0 * va + cw1 * vb);
  if (lane < 32) {
    wpart = fmaf(q1, cw0 * ks10 + cw1 * ks11, wpart);
    float ua = dsampV(kimg, s_om, g1, i0, y, x, c1);
    float ub = dsampV(kimg, s_om, g1, i1, y, x, c1);
    vre[((long)pair * 16384 + bp) * 96 + c1] = f2h(cw0 * ua + cw1 * ub);
  }
#pragma unroll
  for (int off = 32; off > 0; off >>= 1) wpart += __shfl_xor(wpart, off, 64);
  if (lane == 0) w_buf[(long)pair * 16384 + bp] = wpart;
}

// ---------------- merge: softmax over the 2 source frames -> f_t fp32 flat ----------------
__global__ __launch_bounds__(256) void merge_k(const float* __restrict__ w_buf,
                                               const f16* __restrict__ vre,
                                               float* __restrict__ f_t) {
  long idx = (long)blockIdx.x * 256 + threadIdx.x;
  const long TOT = (long)4 * 3 * PIXN * 24;
  if (idx >= TOT) return;
  int c4 = idx % 24;
  long t = idx / 24;
  int p = t % PIXN;
  long t2 = t / PIXN;
  int jj = t2 % 3;
  int b = (int)(t2 / 3);
  long bpi = (long)b * PIXN + p;
  int pr0 = jj * 2, pr1 = jj * 2 + 1;
  float w0 = w_buf[(long)pr0 * 16384 + bpi];
  float w1 = w_buf[(long)pr1 * 16384 + bpi];
  float mx = fmaxf(w0, w1);
  float e0 = expf(w0 - mx), e1 = expf(w1 - mx);
  float inv = 1.f / (e0 + e1);
  float s0 = e0 * inv, s1 = e1 * inv;
  const f16* va = &vre[((long)pr0 * 16384 + bpi) * 96 + c4 * 4];
  const f16* vb = &vre[((long)pr1 * 16384 + bpi) * 96 + c4 * 4];
  float4 r;
  r.x = s0 * h2f(va[0]) + s1 * h2f(vb[0]);
  r.y = s0 * h2f(va[1]) + s1 * h2f(vb[1]);
  r.z = s0 * h2f(va[2]) + s1 * h2f(vb[2]);
  r.w = s0 * h2f(va[3]) + s1 * h2f(vb[3]);
  *reinterpret_cast<float4*>(f_t + ((long)(b * 3 + jj) * PIXN + p) * 96 + c4 * 4) = r;
}

// ---------------- host ----------------
extern "C" void kernel_launch(void* const* d_in, const int* in_sizes, int n_in,
                              void* d_out, int out_size, void* d_ws, size_t ws_size,
                              hipStream_t stream) {
  const float* fea = (const float*)d_in[0];
  const float* cf_w = (const float*)d_in[1];
  const float* cf_b = (const float*)d_in[2];
  const float* wq = (const float*)d_in[3];
  const float* bq = (const float*)d_in[4];
  const float* wk = (const float*)d_in[5];
  const float* bk = (const float*)d_in[6];
  const float* wv = (const float*)d_in[7];
  const float* bv = (const float*)d_in[8];
  const float* oc1_w = (const float*)d_in[9];
  const float* oc1_b = (const float*)d_in[10];
  const float* oc2_w = (const float*)d_in[11];
  const float* oc2_b = (const float*)d_in[12];
  const float* om_w = (const float*)d_in[13];
  const float* om_b = (const float*)d_in[14];
  const float* cl_w = (const float*)d_in[15];
  const float* cl_b = (const float*)d_in[16];

  char* base = (char*)d_ws;
  size_t o = 0;
  auto carve = [&](size_t bytes) { char* p = base + o; o += (bytes + 255) & ~255UL; return p; };

  float* T0 = (float*)carve(55296UL * 4);
  float* TAB = (float*)carve(165888UL * 4);
  float* T2 = (float*)carve(82944UL * 4);
  float* T3 = (float*)carve(193536UL * 4);   // om weights padded to 224 oc
  float* T4 = (float*)carve(55296UL * 4);
  float* WQKV = (float*)carve(27648UL * 4);
  float* BQKV = (float*)carve(288UL * 4);
  float* B3p = (float*)carve(224UL * 4);     // om bias padded

  // Z: emb (4.7M floats) early; om (22.0M, stride 224) later (emb dead)
  float* Z = (float*)carve(22020096UL * 4);
  float* emb_t = Z;
  float* om_t = Z;
  float* qkv_t = (float*)carve(14155776UL * 4);
  float* U_t = (float*)carve(4718592UL * 4);
  float* V_t = (float*)carve(4718592UL * 4);
  float* off2_t = (float*)carve(9437184UL * 4);
  float* w_buf = (float*)carve(98304UL * 4);
  float* f_t = U_t;
  f16* vre_b = (f16*)V_t;

  // --- all weight prep in one launch (8 jobs on grid.y) ---
  prep_all<<<dim3(756, 8), 256, 0, stream>>>(cf_w, oc1_w, oc2_w, om_w, cl_w, om_b,
                                             wq, wk, wv, bq, bk, bv,
                                             T0, TAB, T2, T3, T4, WQKV, BQKV, B3p);

  // --- emb conv (fp32): NCHW in -> NHWC flat; NOCG=48 ---
  conv3x3v4<64, 96, 2, ACT_NONE, IN_NCHW, OUT_FLAT, false><<<dim3(16, 12, 2), 256, 0, stream>>>(
      fea, nullptr, nullptr, T0, cf_b, emb_t, nullptr);
  // --- qkv 1x1 (fp32) ---
  gemm1x1v2<<<dim3(16, 12, 3), 256, 0, stream>>>(emb_t, WQKV, BQKV, qkv_t);

  // --- off1 split: U = convA(q_img), V = convB(k_img); NOCG=48 ---
  conv3x3v4<96, 96, 2, ACT_NONE, IN_FLAT, OUT_FLAT, true><<<dim3(16, 24, 2), 256, 0, stream>>>(
      qkv_t, nullptr, nullptr, TAB, nullptr, U_t, nullptr);

  // --- off2 with fused off1 (stage lrelu(U+V+b1)); NOCG=48 ---
  conv3x3v4<96, 96, 2, ACT_LRELU, IN_UVPAIR, OUT_FLAT, false><<<dim3(16, 24, 2), 256, 0, stream>>>(
      U_t, V_t, oc1_b, T2, oc2_b, off2_t, nullptr);

  // --- om conv: COUT padded to 224, CG=4 (NOCG=56), fused sigmoid ---
  conv3x3v4<96, 224, 4, ACT_SIG144, IN_FLAT, OUT_FLAT, false><<<dim3(16, 24, 4), 256, 0, stream>>>(
      off2_t, nullptr, nullptr, T3, B3p, om_t, nullptr);

  // --- fused deformable attention (fp32 selection path; om stride 224) ---
  attn2_k<<<dim3(4096, 6), 256, 0, stream>>>(qkv_t, om_t, w_buf, vre_b);
  merge_k<<<4608, 256, 0, stream>>>(w_buf, vre_b, f_t);

  // --- final conv + residual -> NCHW fp32; NOCG=32 ---
  conv3x3v4<96, 64, 2, ACT_NONE, IN_FLAT, OUT_NCHWRES, false><<<dim3(16, 12, 2), 256, 0, stream>>>(
      f_t, nullptr, nullptr, T4, cl_b, (float*)d_out, fea);
}

// Round 13
// 1726.566 us; speedup vs baseline: 1.0786x; 1.0786x over previous
//
#include <hip/hip_runtime.h>
#include <math.h>

#define PIXN 4096

typedef _Float16 f16;

__device__ __forceinline__ f16 f2h(float f) { return (f16)f; }
__device__ __forceinline__ float h2f(f16 h) { return (float)h; }

enum { ACT_NONE = 0, ACT_LRELU = 1, ACT_SIG144 = 2 };
enum { IN_NCHW = 0, IN_FLAT = 1, IN_UVPAIR = 2 };
enum { OUT_FLAT = 0, OUT_NCHWRES = 1 };

// ---------------- fused weight prep (7 jobs) ----------------
__device__ __forceinline__ void wtrans_dev(const float* __restrict__ w, float* __restrict__ wT,
                                           int srcCIN, int cinOff, int dstCIN, int COUTv,
                                           int total, int idx) {
  if (idx >= total) return;
  int co = idx % COUTv;
  int t = idx / COUTv;
  int ci = t % dstCIN;
  int tap = t / dstCIN;
  wT[idx] = w[((long)co * srcCIN + cinOff + ci) * 9 + tap];
}

__global__ __launch_bounds__(256) void prep_all(
    const float* __restrict__ cf_w, const float* __restrict__ oc1_w,
    const float* __restrict__ oc2_w, const float* __restrict__ om_w,
    const float* __restrict__ cl_w,
    const float* __restrict__ wq, const float* __restrict__ wk, const float* __restrict__ wv,
    const float* __restrict__ bq, const float* __restrict__ bk, const float* __restrict__ bv,
    float* __restrict__ T0, float* __restrict__ TAB, float* __restrict__ T2,
    float* __restrict__ T3, float* __restrict__ T4,
    float* __restrict__ WQKV, float* __restrict__ BQKV) {
  int idx = blockIdx.x * 256 + threadIdx.x;
  switch (blockIdx.y) {
    case 0: wtrans_dev(cf_w, T0, 64, 0, 64, 96, 55296, idx); break;
    case 1: wtrans_dev(oc1_w, TAB, 192, 0, 96, 96, 82944, idx); break;
    case 2: wtrans_dev(oc1_w, TAB + 82944, 192, 96, 96, 96, 82944, idx); break;
    case 3: wtrans_dev(oc2_w, T2, 96, 0, 96, 96, 82944, idx); break;
    case 4: wtrans_dev(om_w, T3, 96, 0, 96, 216, 186624, idx); break;
    case 5: wtrans_dev(cl_w, T4, 96, 0, 96, 64, 55296, idx); break;
    default: {
      if (idx < 96 * 288) {
        int e288 = idx % 288;
        int c = idx / 288;
        int m = e288 / 96, e = e288 % 96;
        const float* wm = (m == 0) ? wq : (m == 1) ? wk : wv;
        WQKV[idx] = wm[e * 96 + c];
      }
      if (idx < 288) {
        int m = idx / 96, e = idx % 96;
        const float* bm = (m == 0) ? bq : (m == 1) ? bk : bv;
        BQKV[idx] = bm[e];
      }
    }
  }
}

// ---------------- fp32 3x3 conv, GEMV-style (v4) ----------------
// Block 256 = 4 waves = 4 output rows; all waves share one oc-slice.
// Weights thread-uniform -> s_load; LDS 6x66x8cin stride-9 = 14.3 KB.
// IN_UVPAIR: stage lrelu(U[jj] + V[ii] + bias_in) (fused off1).
// NOCG must stay <= 48: NOCG=56 spilled (round 12: VGPR 44 + scratch, +24%).
template <int CIN, int COUT, int CG, int ACT, int IMODE, int OMODE, bool QKVIN>
__global__ __launch_bounds__(256) void conv3x3v4(
    const float* __restrict__ in, const float* __restrict__ in2,
    const float* __restrict__ bias_in,
    const float* __restrict__ wT,
    const float* __restrict__ bias,
    float* __restrict__ out,
    const float* __restrict__ resid) {
  constexpr int NOCG = COUT / CG;
  constexpr int NCH = CIN / 8;
  const int y0 = blockIdx.x * 4;
  const int iz = blockIdx.y;
  const int cg = blockIdx.z;
  const int tid = threadIdx.x;
  const int x = tid & 63;
  const int wv = tid >> 6;
  const int ocb = cg * NOCG;

  __shared__ float lds[6 * 66 * 9];

  const float* baseA;
  const float* baseB2 = nullptr;
  const float* wTe = wT;
  if constexpr (QKVIN) {
    int sel = iz / 12, img = iz % 12;
    baseA = in + (long)img * (PIXN * 288) + sel * 96;
    wTe = wT + (long)sel * (9 * 96 * COUT);
  } else if constexpr (IMODE == IN_UVPAIR) {
    int pair = iz >> 2, b = iz & 3;
    int jj = pair >> 1, rr = pair & 1;
    int ii = (rr == 0) ? (jj == 0 ? 1 : 0) : (jj == 2 ? 1 : 2);
    baseA = in + (long)(b * 3 + jj) * (PIXN * 96);
    baseB2 = in2 + (long)(b * 3 + ii) * (PIXN * 96);
  } else if constexpr (IMODE == IN_NCHW) {
    baseA = in + (long)iz * (CIN * PIXN);
  } else {
    baseA = in + (long)iz * (PIXN * CIN);
  }
  constexpr int LDV = QKVIN ? 288 : CIN;

  float acc[NOCG];
#pragma unroll
  for (int j = 0; j < NOCG; ++j) acc[j] = bias ? bias[ocb + j] : 0.f;

#pragma unroll 1
  for (int ch = 0; ch < NCH; ++ch) {
    __syncthreads();
    if constexpr (IMODE == IN_NCHW) {
      for (int i = tid; i < 8 * 396; i += 256) {
        int cin = i / 396;
        int t = i - cin * 396;
        int r = t / 66, px = t - r * 66;
        int yy = y0 - 1 + r, xx = px - 1;
        float v = 0.f;
        if ((unsigned)yy < 64u && (unsigned)xx < 64u)
          v = baseA[(long)(ch * 8 + cin) * PIXN + yy * 64 + xx];
        lds[t * 9 + cin] = v;
      }
    } else if constexpr (IMODE == IN_UVPAIR) {
      for (int i = tid; i < 396 * 2; i += 256) {
        int c4 = i & 1, t = i >> 1;
        int r = t / 66, px = t - r * 66;
        int yy = y0 - 1 + r, xx = px - 1;
        float4 rv = make_float4(0.f, 0.f, 0.f, 0.f);
        if ((unsigned)yy < 64u && (unsigned)xx < 64u) {
          long off = (long)(yy * 64 + xx) * 96 + ch * 8 + c4 * 4;
          float4 u = *reinterpret_cast<const float4*>(baseA + off);
          float4 vv = *reinterpret_cast<const float4*>(baseB2 + off);
          float4 bi = *reinterpret_cast<const float4*>(bias_in + ch * 8 + c4 * 4);
          rv.x = u.x + vv.x + bi.x; rv.x = rv.x >= 0.f ? rv.x : 0.1f * rv.x;
          rv.y = u.y + vv.y + bi.y; rv.y = rv.y >= 0.f ? rv.y : 0.1f * rv.y;
          rv.z = u.z + vv.z + bi.z; rv.z = rv.z >= 0.f ? rv.z : 0.1f * rv.z;
          rv.w = u.w + vv.w + bi.w; rv.w = rv.w >= 0.f ? rv.w : 0.1f * rv.w;
        }
        int b0 = t * 9 + c4 * 4;
        lds[b0] = rv.x; lds[b0 + 1] = rv.y; lds[b0 + 2] = rv.z; lds[b0 + 3] = rv.w;
      }
    } else {
      for (int i = tid; i < 396 * 2; i += 256) {
        int c4 = i & 1, t = i >> 1;
        int r = t / 66, px = t - r * 66;
        int yy = y0 - 1 + r, xx = px - 1;
        float4 v = make_float4(0.f, 0.f, 0.f, 0.f);
        if ((unsigned)yy < 64u && (unsigned)xx < 64u)
          v = *reinterpret_cast<const float4*>(
              baseA + (long)(yy * 64 + xx) * LDV + ch * 8 + c4 * 4);
        int b0 = t * 9 + c4 * 4;
        lds[b0] = v.x; lds[b0 + 1] = v.y; lds[b0 + 2] = v.z; lds[b0 + 3] = v.w;
      }
    }
    __syncthreads();

#pragma unroll
    for (int r = 0; r < 3; ++r) {
#pragma unroll
      for (int kx = 0; kx < 3; ++kx) {
        const float* wp = wTe + ((long)((r * 3 + kx) * CIN + ch * 8)) * COUT + ocb;
        const int lb = ((wv + r) * 66 + x + kx) * 9;
#pragma unroll 2
        for (int cin = 0; cin < 8; ++cin) {
          float xv = lds[lb + cin];
          const float* wpc = wp + cin * COUT;
#pragma unroll
          for (int j = 0; j < NOCG; ++j)
            acc[j] = fmaf(xv, wpc[j], acc[j]);
        }
      }
    }
  }

  const int yo = y0 + wv;
#pragma unroll
  for (int j = 0; j < NOCG; ++j) {
    if (ACT == ACT_LRELU) acc[j] = acc[j] >= 0.f ? acc[j] : 0.1f * acc[j];
    if (ACT == ACT_SIG144) {
      if (ocb + j >= 144) acc[j] = 1.f / (1.f + expf(-acc[j]));
    }
  }
  if constexpr (OMODE == OUT_FLAT) {
    float* orow = out + ((long)iz * PIXN + yo * 64 + x) * COUT + ocb;
#pragma unroll
    for (int j4 = 0; j4 < NOCG / 4; ++j4) {
      float4 v = make_float4(acc[j4 * 4], acc[j4 * 4 + 1], acc[j4 * 4 + 2], acc[j4 * 4 + 3]);
      *reinterpret_cast<float4*>(orow + j4 * 4) = v;
    }
  } else {
#pragma unroll
    for (int j = 0; j < NOCG; ++j) {
      int oc = ocb + j;
      long oo = (long)iz * (COUT * PIXN) + (long)oc * PIXN + yo * 64 + x;
      out[oo] = acc[j] + resid[oo];
    }
  }
}

// ---------------- 1x1 qkv projection, GEMV-style ----------------
__global__ __launch_bounds__(256) void gemm1x1v2(const float* __restrict__ in,
                                                 const float* __restrict__ wT,
                                                 const float* __restrict__ bias,
                                                 float* __restrict__ out) {
  const int pcb = blockIdx.x;
  const int img = blockIdx.y;
  const int cg = blockIdx.z;
  const int tid = threadIdx.x;
  __shared__ float lds[256 * 33];
  float acc[96];
#pragma unroll
  for (int j = 0; j < 96; ++j) acc[j] = bias[cg * 96 + j];
  const float* ibase = in + ((long)img * PIXN + pcb * 256) * 96;
#pragma unroll 1
  for (int cc = 0; cc < 96; cc += 32) {
    __syncthreads();
    for (int i = tid; i < 2048; i += 256) {
      int px = i >> 3, c4 = i & 7;
      float4 v = *reinterpret_cast<const float4*>(ibase + (long)px * 96 + cc + c4 * 4);
      int b0 = px * 33 + c4 * 4;
      lds[b0] = v.x; lds[b0 + 1] = v.y; lds[b0 + 2] = v.z; lds[b0 + 3] = v.w;
    }
    __syncthreads();
#pragma unroll 2
    for (int c = 0; c < 32; ++c) {
      float xv = lds[tid * 33 + c];
      const float* wp = wT + (long)(cc + c) * 288 + cg * 96;
#pragma unroll
      for (int j = 0; j < 96; ++j) acc[j] = fmaf(xv, wp[j], acc[j]);
    }
  }
  float* orow = out + ((long)img * PIXN + pcb * 256 + tid) * 288 + cg * 96;
#pragma unroll
  for (int j4 = 0; j4 < 24; ++j4) {
    float4 v = make_float4(acc[j4 * 4], acc[j4 * 4 + 1], acc[j4 * 4 + 2], acc[j4 * 4 + 3]);
    *reinterpret_cast<float4*>(orow + j4 * 4) = v;
  }
}

// ---------------- deformable sampling helpers (fp32; mask pre-sigmoided) ----------------
__device__ __forceinline__ float dsampK(const float* __restrict__ kimg,
                                        const float* __restrict__ s_om,
                                        int g, int n, int y, int x, int c) {
  float oy = s_om[g * 9 + n];
  float ox = s_om[72 + g * 9 + n];
  float m = s_om[144 + g * 9 + n];
  float py = oy + (float)(y + n / 3 - 1);
  float px = ox + (float)(x + n % 3 - 1);
  float y0 = floorf(py), x0 = floorf(px);
  float wy = py - y0, wx = px - x0;
  float acc = 0.f;
#pragma unroll
  for (int dy = 0; dy < 2; ++dy) {
#pragma unroll
    for (int dx = 0; dx < 2; ++dx) {
      float yc = y0 + dy, xc = x0 + dx;
      if (yc >= 0.f && yc < 64.f && xc >= 0.f && xc < 64.f) {
        float w = (dy ? wy : 1.f - wy) * (dx ? wx : 1.f - wx);
        acc = fmaf(w, kimg[(long)((int)yc * 64 + (int)xc) * 288 + 96 + c], acc);
      }
    }
  }
  return acc * m;
}

__device__ __forceinline__ float dsampV(const float* __restrict__ kimg,
                                        const float* __restrict__ s_om,
                                        int g, int n, int y, int x, int c) {
  float oy = s_om[g * 9 + n];
  float ox = s_om[72 + g * 9 + n];
  float m = s_om[144 + g * 9 + n];
  float py = oy + (float)(y + n / 3 - 1);
  float px = ox + (float)(x + n % 3 - 1);
  float y0 = floorf(py), x0 = floorf(px);
  float wy = py - y0, wx = px - x0;
  float acc = 0.f;
#pragma unroll
  for (int dy = 0; dy < 2; ++dy) {
#pragma unroll
    for (int dx = 0; dx < 2; ++dx) {
      float yc = y0 + dy, xc = x0 + dx;
      if (yc >= 0.f && yc < 64.f && xc >= 0.f && xc < 64.f) {
        float w = (dy ? wy : 1.f - wy) * (dx ? wx : 1.f - wx);
        acc = fmaf(w, kimg[(long)((int)yc * 64 + (int)xc) * 288 + 192 + c], acc);
      }
    }
  }
  return acc * m;
}

// ---------------- attn v2: 4 px/block, cached sampled-K, V-only select ----------------
__global__ __launch_bounds__(256) void attn2_k(const float* __restrict__ qkv,
                                               const float* __restrict__ om,
                                               float* __restrict__ w_buf,
                                               f16* __restrict__ vre) {
  const int pair = blockIdx.y;
  const int jj = pair >> 1, rr = pair & 1;
  const int ii = (rr == 0) ? (jj == 0 ? 1 : 0) : (jj == 2 ? 1 : 2);
  const int wv = threadIdx.x >> 6;
  const int lane = threadIdx.x & 63;
  const int bp = blockIdx.x * 4 + wv;
  const int b = bp >> 12;
  const int p = bp & 4095;
  const int y = p >> 6, x = p & 63;

  __shared__ float s_om_all[4 * 216];
  float* s_om = s_om_all + wv * 216;
  const float* omrow = om + ((long)pair * 4 * PIXN + bp) * 216;
  for (int i = lane; i < 216; i += 64) s_om[i] = omrow[i];
  __syncthreads();

  const float* qrow = qkv + ((long)(b * 3 + jj) * PIXN + p) * 288;
  const float* kimg = qkv + (long)(b * 3 + ii) * PIXN * 288;
  float q0 = qrow[lane];
  float q1 = 0.f;
  if (lane < 32) q1 = qrow[64 + lane];
  const int c0 = lane, g0 = lane / 12;
  const int c1 = 64 + lane, g1 = (64 + lane) / 12;

  float rel[9], ka0[9], ka1[9];
#pragma unroll
  for (int n = 0; n < 9; ++n) {
    ka0[n] = dsampK(kimg, s_om, g0, n, y, x, c0);
    float part = q0 * ka0[n];
    ka1[n] = 0.f;
    if (lane < 32) {
      ka1[n] = dsampK(kimg, s_om, g1, n, y, x, c1);
      part = fmaf(q1, ka1[n], part);
    }
#pragma unroll
    for (int off = 32; off > 0; off >>= 1) part += __shfl_xor(part, off, 64);
    rel[n] = part;
  }
  int i0 = 0; float v0 = rel[0]; float ks00 = ka0[0], ks10 = ka1[0];
#pragma unroll
  for (int n = 1; n < 9; ++n) {
    bool t = rel[n] > v0;
    v0 = t ? rel[n] : v0; i0 = t ? n : i0;
    ks00 = t ? ka0[n] : ks00; ks10 = t ? ka1[n] : ks10;
  }
  int i1 = 0; float v1 = -3.4e38f; float ks01 = 0.f, ks11 = 0.f;
#pragma unroll
  for (int n = 0; n < 9; ++n) {
    bool t = (n != i0) && rel[n] > v1;
    v1 = t ? rel[n] : v1; i1 = t ? n : i1;
    ks01 = t ? ka0[n] : ks01; ks11 = t ? ka1[n] : ks11;
  }
  float e = expf(v1 - v0);
  float cw0 = 1.f / (1.f + e);
  float cw1 = e * cw0;

  float wpart = q0 * (cw0 * ks00 + cw1 * ks01);
  float va = dsampV(kimg, s_om, g0, i0, y, x, c0);
  float vb = dsampV(kimg, s_om, g0, i1, y, x, c0);
  vre[((long)pair * 16384 + bp) * 96 + c0] = f2h(cw0 * va + cw1 * vb);
  if (lane < 32) {
    wpart = fmaf(q1, cw0 * ks10 + cw1 * ks11, wpart);
    float ua = dsampV(kimg, s_om, g1, i0, y, x, c1);
    float ub = dsampV(kimg, s_om, g1, i1, y, x, c1);
    vre[((long)pair * 16384 + bp) * 96 + c1] = f2h(cw0 * ua + cw1 * ub);
  }
#pragma unroll
  for (int off = 32; off > 0; off >>= 1) wpart += __shfl_xor(wpart, off, 64);
  if (lane == 0) w_buf[(long)pair * 16384 + bp] = wpart;
}

// ---------------- merge: softmax over the 2 source frames -> f_t fp32 flat ----------------
__global__ __launch_bounds__(256) void merge_k(const float* __restrict__ w_buf,
                                               const f16* __restrict__ vre,
                                               float* __restrict__ f_t) {
  long idx = (long)blockIdx.x * 256 + threadIdx.x;
  const long TOT = (long)4 * 3 * PIXN * 24;
  if (idx >= TOT) return;
  int c4 = idx % 24;
  long t = idx / 24;
  int p = t % PIXN;
  long t2 = t / PIXN;
  int jj = t2 % 3;
  int b = (int)(t2 / 3);
  long bpi = (long)b * PIXN + p;
  int pr0 = jj * 2, pr1 = jj * 2 + 1;
  float w0 = w_buf[(long)pr0 * 16384 + bpi];
  float w1 = w_buf[(long)pr1 * 16384 + bpi];
  float mx = fmaxf(w0, w1);
  float e0 = expf(w0 - mx), e1 = expf(w1 - mx);
  float inv = 1.f / (e0 + e1);
  float s0 = e0 * inv, s1 = e1 * inv;
  const f16* va = &vre[((long)pr0 * 16384 + bpi) * 96 + c4 * 4];
  const f16* vb = &vre[((long)pr1 * 16384 + bpi) * 96 + c4 * 4];
  float4 r;
  r.x = s0 * h2f(va[0]) + s1 * h2f(vb[0]);
  r.y = s0 * h2f(va[1]) + s1 * h2f(vb[1]);
  r.z = s0 * h2f(va[2]) + s1 * h2f(vb[2]);
  r.w = s0 * h2f(va[3]) + s1 * h2f(vb[3]);
  *reinterpret_cast<float4*>(f_t + ((long)(b * 3 + jj) * PIXN + p) * 96 + c4 * 4) = r;
}

// ---------------- host ----------------
extern "C" void kernel_launch(void* const* d_in, const int* in_sizes, int n_in,
                              void* d_out, int out_size, void* d_ws, size_t ws_size,
                              hipStream_t stream) {
  const float* fea = (const float*)d_in[0];
  const float* cf_w = (const float*)d_in[1];
  const float* cf_b = (const float*)d_in[2];
  const float* wq = (const float*)d_in[3];
  const float* bq = (const float*)d_in[4];
  const float* wk = (const float*)d_in[5];
  const float* bk = (const float*)d_in[6];
  const float* wv = (const float*)d_in[7];
  const float* bv = (const float*)d_in[8];
  const float* oc1_w = (const float*)d_in[9];
  const float* oc1_b = (const float*)d_in[10];
  const float* oc2_w = (const float*)d_in[11];
  const float* oc2_b = (const float*)d_in[12];
  const float* om_w = (const float*)d_in[13];
  const float* om_b = (const float*)d_in[14];
  const float* cl_w = (const float*)d_in[15];
  const float* cl_b = (const float*)d_in[16];

  char* base = (char*)d_ws;
  size_t o = 0;
  auto carve = [&](size_t bytes) { char* p = base + o; o += (bytes + 255) & ~255UL; return p; };

  float* T0 = (float*)carve(55296UL * 4);
  float* TAB = (float*)carve(165888UL * 4);
  float* T2 = (float*)carve(82944UL * 4);
  float* T3 = (float*)carve(186624UL * 4);
  float* T4 = (float*)carve(55296UL * 4);
  float* WQKV = (float*)carve(27648UL * 4);
  float* BQKV = (float*)carve(288UL * 4);

  // Z: emb (4.7M floats) early; om (21.2M, stride 216) later (emb dead)
  float* Z = (float*)carve(21233664UL * 4);
  float* emb_t = Z;
  float* om_t = Z;
  float* qkv_t = (float*)carve(14155776UL * 4);
  float* U_t = (float*)carve(4718592UL * 4);
  float* V_t = (float*)carve(4718592UL * 4);
  float* off2_t = (float*)carve(9437184UL * 4);
  float* w_buf = (float*)carve(98304UL * 4);
  float* f_t = U_t;
  f16* vre_b = (f16*)V_t;

  // --- all weight prep in one launch (7 jobs on grid.y) ---
  prep_all<<<dim3(729, 7), 256, 0, stream>>>(cf_w, oc1_w, oc2_w, om_w, cl_w,
                                             wq, wk, wv, bq, bk, bv,
                                             T0, TAB, T2, T3, T4, WQKV, BQKV);

  // --- emb conv (fp32): NCHW in -> NHWC flat; NOCG=48 ---
  conv3x3v4<64, 96, 2, ACT_NONE, IN_NCHW, OUT_FLAT, false><<<dim3(16, 12, 2), 256, 0, stream>>>(
      fea, nullptr, nullptr, T0, cf_b, emb_t, nullptr);
  // --- qkv 1x1 (fp32) ---
  gemm1x1v2<<<dim3(16, 12, 3), 256, 0, stream>>>(emb_t, WQKV, BQKV, qkv_t);

  // --- off1 split: U = convA(q_img), V = convB(k_img); NOCG=48 ---
  conv3x3v4<96, 96, 2, ACT_NONE, IN_FLAT, OUT_FLAT, true><<<dim3(16, 24, 2), 256, 0, stream>>>(
      qkv_t, nullptr, nullptr, TAB, nullptr, U_t, nullptr);

  // --- off2 with fused off1 (stage lrelu(U+V+b1)); NOCG=48 ---
  conv3x3v4<96, 96, 2, ACT_LRELU, IN_UVPAIR, OUT_FLAT, false><<<dim3(16, 24, 2), 256, 0, stream>>>(
      U_t, V_t, oc1_b, T2, oc2_b, off2_t, nullptr);

  // --- om conv: round-11 proven config (CG=6, NOCG=36) + fused sigmoid ---
  conv3x3v4<96, 216, 6, ACT_SIG144, IN_FLAT, OUT_FLAT, false><<<dim3(16, 24, 6), 256, 0, stream>>>(
      off2_t, nullptr, nullptr, T3, om_b, om_t, nullptr);

  // --- fused deformable attention (fp32 selection path; om stride 216) ---
  attn2_k<<<dim3(4096, 6), 256, 0, stream>>>(qkv_t, om_t, w_buf, vre_b);
  merge_k<<<4608, 256, 0, stream>>>(w_buf, vre_b, f_t);

  // --- final conv + residual -> NCHW fp32; NOCG=32 ---
  conv3x3v4<96, 64, 2, ACT_NONE, IN_FLAT, OUT_NCHWRES, false><<<dim3(16, 12, 2), 256, 0, stream>>>(
      f_t, nullptr, nullptr, T4, cl_b, (float*)d_out, fea);
}